// Round 5
// baseline (958.745 us; speedup 1.0000x reference)
//
#include <hip/hip_runtime.h>

// GraphConvolution: out = A_coo @ (x @ W)
// x: [100000, 256] f32, W: [256, 64] f32, A: 1.6M edges (rows, cols int32, vals f32)
//
// R4 -> R5: fine CSR scatter (141us, WRITE_SIZE=100MB: every 8B store dirtied
// a full 64B line, random positions + cross-XCD ownership defeat L2 merging)
// replaced by 128-row coarse buckets:
//   coarse_hist(782) -> coarse_scan -> bin_edges (block-chunk reservation =>
//   XCD-local contiguous runs, L2-mergeable) -> accum_tile (LDS f32 atomics
//   into padded 128x66 tile, single coalesced out write).

#define KDIM 256
#define MDIM 64
#define BSHIFT 7              // 128 rows per bucket
#define BMAX 1024             // max buckets supported by LDS tables

// ---------------------------------------------------------------- GEMM
// Block tile 128 rows x 64 feats, K-tile 64. Thread tile 8 rows x 4 feats.
__global__ __launch_bounds__(256) void gemm_xw(
    const float* __restrict__ x, const float* __restrict__ W,
    float* __restrict__ support, int nrows)
{
    __shared__ float xs[128][64];   // 32 KB, col-group XOR swizzle
    __shared__ float ws2[64][64];   // 16 KB, ws2[kk][f]
    const int tid = threadIdx.x;
    const int tr  = tid >> 4;
    const int f0  = (tid & 15) * 4;
    const int swz = tr & 3;
    const int row0 = blockIdx.x * 128;

    float acc[8][4];
    #pragma unroll
    for (int i = 0; i < 8; ++i)
        #pragma unroll
        for (int j = 0; j < 4; ++j) acc[i][j] = 0.f;

    for (int kt = 0; kt < KDIM; kt += 64) {
        __syncthreads();
        #pragma unroll
        for (int i = 0; i < 8; ++i) {
            int slot = tid + i * 256;
            int r = slot >> 4;
            int q = slot & 15;
            int grow = row0 + r;
            float4 v = make_float4(0.f, 0.f, 0.f, 0.f);
            if (grow < nrows)
                v = *reinterpret_cast<const float4*>(
                        &x[(size_t)grow * KDIM + kt + q * 4]);
            int qs = q ^ ((r >> 3) & 3);
            *reinterpret_cast<float4*>(&xs[r][qs * 4]) = v;
        }
        #pragma unroll
        for (int i = 0; i < 4; ++i) {
            int slot = tid + i * 256;
            int kk = slot >> 4;
            int q = slot & 15;
            float4 v = *reinterpret_cast<const float4*>(
                           &W[(size_t)(kt + kk) * MDIM + q * 4]);
            *reinterpret_cast<float4*>(&ws2[kk][q * 4]) = v;
        }
        __syncthreads();

        #pragma unroll 2
        for (int kk = 0; kk < 64; kk += 4) {
            const int q4 = kk >> 2;
            float4 xv[8];
            #pragma unroll
            for (int i = 0; i < 8; ++i)
                xv[i] = *reinterpret_cast<const float4*>(
                            &xs[tr * 8 + i][(q4 ^ swz) * 4]);
            #pragma unroll
            for (int k2 = 0; k2 < 4; ++k2) {
                float4 wv = *reinterpret_cast<const float4*>(&ws2[kk + k2][f0]);
                #pragma unroll
                for (int i = 0; i < 8; ++i) {
                    const float xk = (k2 == 0) ? xv[i].x :
                                     (k2 == 1) ? xv[i].y :
                                     (k2 == 2) ? xv[i].z : xv[i].w;
                    acc[i][0] = fmaf(xk, wv.x, acc[i][0]);
                    acc[i][1] = fmaf(xk, wv.y, acc[i][1]);
                    acc[i][2] = fmaf(xk, wv.z, acc[i][2]);
                    acc[i][3] = fmaf(xk, wv.w, acc[i][3]);
                }
            }
        }
    }

    #pragma unroll
    for (int i = 0; i < 8; ++i) {
        int grow = row0 + tr * 8 + i;
        if (grow < nrows) {
            float4 v = make_float4(acc[i][0], acc[i][1], acc[i][2], acc[i][3]);
            *reinterpret_cast<float4*>(&support[(size_t)grow * MDIM + f0]) = v;
        }
    }
}

// ------------------------------------------------- coarse bucket build
// Per-block LDS histogram of 128-row buckets, one global atomic per bucket.
__global__ __launch_bounds__(256) void coarse_hist(
    const int* __restrict__ rows, int* __restrict__ counts,
    int nedges, int nbuckets)
{
    __shared__ int lb[BMAX];
    const int t = threadIdx.x;
    for (int i = t; i < nbuckets; i += 256) lb[i] = 0;
    __syncthreads();
    int e = blockIdx.x * 256 + t;
    const int stride = gridDim.x * 256;
    for (; e < nedges; e += stride)
        atomicAdd(&lb[rows[e] >> BSHIFT], 1);
    __syncthreads();
    for (int i = t; i < nbuckets; i += 256) {
        int c = lb[i];
        if (c) atomicAdd(&counts[i], c);
    }
}

// Single-block exclusive scan (n <= 1024): offsets + cursor seed.
__global__ __launch_bounds__(256) void coarse_scan(
    const int* __restrict__ counts, int* __restrict__ offsets,
    int* __restrict__ cursor, int n)
{
    __shared__ int sh[256];
    const int t = threadIdx.x;
    const int base = t * 4;
    int v0 = 0, v1 = 0, v2 = 0, v3 = 0;
    if (base + 0 < n) v0 = counts[base + 0];
    if (base + 1 < n) v1 = counts[base + 1];
    if (base + 2 < n) v2 = counts[base + 2];
    if (base + 3 < n) v3 = counts[base + 3];
    const int tsum = v0 + v1 + v2 + v3;
    sh[t] = tsum;
    __syncthreads();
    for (int off = 1; off < 256; off <<= 1) {
        int xv = (t >= off) ? sh[t - off] : 0;
        __syncthreads();
        sh[t] += xv;
        __syncthreads();
    }
    int excl = sh[t] - tsum;
    if (base + 0 < n) { offsets[base + 0] = excl; cursor[base + 0] = excl; } excl += v0;
    if (base + 1 < n) { offsets[base + 1] = excl; cursor[base + 1] = excl; } excl += v1;
    if (base + 2 < n) { offsets[base + 2] = excl; cursor[base + 2] = excl; } excl += v2;
    if (base + 3 < n) { offsets[base + 3] = excl; cursor[base + 3] = excl; }
}

// Each block owns a contiguous edge chunk: LDS-hist it, reserve one
// contiguous run per bucket (global atomic), then scatter via LDS cursors.
// A block's stores to a bucket land in a block-private run -> merged in the
// owning XCD's L2 into (near-)full lines.
// Packed record: pk.x = col(17b) | rowlow(7b)<<17 ; pk.y = val bits.
__global__ __launch_bounds__(256) void bin_edges(
    const int* __restrict__ rows, const int* __restrict__ cols,
    const float* __restrict__ vals, int* __restrict__ cursor,
    int2* __restrict__ edata, int nedges, int nbuckets)
{
    __shared__ int lb[BMAX];
    const int t = threadIdx.x;
    const int per = (nedges + gridDim.x - 1) / gridDim.x;
    const int e0 = blockIdx.x * per;
    const int e1 = min(e0 + per, nedges);

    for (int i = t; i < nbuckets; i += 256) lb[i] = 0;
    __syncthreads();
    for (int e = e0 + t; e < e1; e += 256)
        atomicAdd(&lb[rows[e] >> BSHIFT], 1);
    __syncthreads();
    for (int i = t; i < nbuckets; i += 256) {
        int c = lb[i];
        lb[i] = c ? atomicAdd(&cursor[i], c) : 0;   // lb becomes block cursor
    }
    __syncthreads();
    for (int e = e0 + t; e < e1; e += 256) {
        const int r = rows[e];
        const int pos = atomicAdd(&lb[r >> BSHIFT], 1);
        int2 pk;
        pk.x = (cols[e] & 0x1FFFF) | ((r & 127) << 17);
        pk.y = __float_as_int(vals[e]);
        edata[pos] = pk;
    }
}

// --------------------------------------------------- bucket accumulate
// One block per 128-row bucket. Edges contiguous; 16-lane group per edge,
// lane owns 4 features. LDS f32 atomics into padded tile; single coalesced
// out write (no global atomics, no memset of out needed).
__global__ __launch_bounds__(256) void accum_tile(
    const int* __restrict__ offsets, const int* __restrict__ counts,
    const int2* __restrict__ edata, const float* __restrict__ support,
    float* __restrict__ out, int nrows)
{
    __shared__ float tile[128][66];   // +2 pad: rows spread across banks
    const int t = threadIdx.x;
    const int b = blockIdx.x;

    for (int i = t; i < 128 * 66; i += 256) ((float*)tile)[i] = 0.f;
    __syncthreads();

    const int beg = offsets[b];
    const int end = beg + counts[b];
    const int g  = t >> 4;           // 16 edge-groups
    const int f0 = (t & 15) * 4;

    for (int e = beg + g; e < end; e += 16) {
        const int2 pk = edata[e];
        const int c  = pk.x & 0x1FFFF;
        const int rl = (pk.x >> 17) & 127;
        const float v = __int_as_float(pk.y);
        float4 s = *reinterpret_cast<const float4*>(
                       &support[(size_t)c * MDIM + f0]);
        atomicAdd(&tile[rl][f0 + 0], v * s.x);
        atomicAdd(&tile[rl][f0 + 1], v * s.y);
        atomicAdd(&tile[rl][f0 + 2], v * s.z);
        atomicAdd(&tile[rl][f0 + 3], v * s.w);
    }
    __syncthreads();

    const int row0 = b << BSHIFT;
    for (int i = t; i < 128 * 16; i += 256) {
        const int r = i >> 4;
        const int q = i & 15;
        const int grow = row0 + r;
        if (grow < nrows) {
            float4 o = make_float4(tile[r][q * 4 + 0], tile[r][q * 4 + 1],
                                   tile[r][q * 4 + 2], tile[r][q * 4 + 3]);
            *reinterpret_cast<float4*>(&out[(size_t)grow * MDIM + q * 4]) = o;
        }
    }
}

// ----------------------------------------------- fallback atomic scatter
__global__ __launch_bounds__(256) void scatter_edges(
    const int* __restrict__ rows, const int* __restrict__ cols,
    const float* __restrict__ vals, const float* __restrict__ support,
    float* __restrict__ out, int nedges)
{
    const int t = blockIdx.x * blockDim.x + threadIdx.x;
    const int fq = (t & 15) * 4;
    int e = t >> 4;
    const int estride = (gridDim.x * blockDim.x) >> 4;
    for (; e < nedges; e += estride) {
        const int r = rows[e];
        const int c = cols[e];
        const float v = vals[e];
        float4 s = *reinterpret_cast<const float4*>(
                       &support[(size_t)c * MDIM + fq]);
        float* op = &out[(size_t)r * MDIM + fq];
        atomicAdd(op + 0, v * s.x);
        atomicAdd(op + 1, v * s.y);
        atomicAdd(op + 2, v * s.z);
        atomicAdd(op + 3, v * s.w);
    }
}

// ---------------------------------------------------------------- launch
extern "C" void kernel_launch(void* const* d_in, const int* in_sizes, int n_in,
                              void* d_out, int out_size, void* d_ws, size_t ws_size,
                              hipStream_t stream) {
    const float* x    = (const float*)d_in[0];
    const int*   rows = (const int*)d_in[1];
    const int*   cols = (const int*)d_in[2];
    const float* vals = (const float*)d_in[3];
    const float* W    = (const float*)d_in[4];
    float* out = (float*)d_out;

    const int nnodes = in_sizes[0] / KDIM;   // 100000
    const int nedges = in_sizes[1];          // 1600000
    const int nbuckets = (nnodes + 127) >> BSHIFT;   // 782

    auto align256 = [](size_t v) { return (v + 255) & ~(size_t)255; };
    const size_t sz_support = align256((size_t)nnodes * MDIM * 4);
    const size_t sz_bkt     = align256((size_t)BMAX * 4);
    const size_t sz_edata   = align256((size_t)nedges * 8);
    const size_t need = sz_support + 3 * sz_bkt + sz_edata;

    char* w = (char*)d_ws;
    float* support = (float*)w;  w += sz_support;

    gemm_xw<<<dim3((nnodes + 127) / 128), dim3(256), 0, stream>>>(
        x, W, support, nnodes);

    // col packing needs nnodes < 2^17; bucket tables need nbuckets <= BMAX.
    if (ws_size >= need && nbuckets <= BMAX && nnodes <= (1 << 17)) {
        int* counts  = (int*)w;  w += sz_bkt;
        int* offsets = (int*)w;  w += sz_bkt;
        int* cursor  = (int*)w;  w += sz_bkt;
        int2* edata  = (int2*)w;

        hipMemsetAsync(counts, 0, (size_t)nbuckets * 4, stream);

        coarse_hist<<<dim3(256), dim3(256), 0, stream>>>(
            rows, counts, nedges, nbuckets);
        coarse_scan<<<dim3(1), dim3(256), 0, stream>>>(
            counts, offsets, cursor, nbuckets);
        bin_edges<<<dim3(256), dim3(256), 0, stream>>>(
            rows, cols, vals, cursor, edata, nedges, nbuckets);
        accum_tile<<<dim3(nbuckets), dim3(256), 0, stream>>>(
            offsets, counts, edata, support, out, nnodes);
    } else {
        hipMemsetAsync(d_out, 0, (size_t)out_size * sizeof(float), stream);
        scatter_edges<<<dim3(4096), dim3(256), 0, stream>>>(
            rows, cols, vals, support, out, nedges);
    }
}